// Round 1
// baseline (884.975 us; speedup 1.0000x reference)
//
#include <hip/hip_runtime.h>

#define NN 100000
#define EE 1600000
#define ELN 200000

// ----------------- degree count -----------------
__global__ void count_deg_kernel(const int* __restrict__ dst, int* __restrict__ deg, int E) {
    int e = blockIdx.x * blockDim.x + threadIdx.x;
    if (e < E) atomicAdd(&deg[dst[e]], 1);
}

__global__ void dinv_kernel(const int* __restrict__ deg, float* __restrict__ dinv, int n) {
    int i = blockIdx.x * blockDim.x + threadIdx.x;
    if (i < n) dinv[i] = rsqrtf((float)deg[i] + 1.0f);
}

// ----------------- exclusive scan (3-phase) -----------------
__global__ __launch_bounds__(256) void scan_partial_kernel(const int* __restrict__ deg,
                                                           int* __restrict__ blksum, int n) {
    __shared__ int sm[256];
    int base = blockIdx.x * 1024;
    int s = 0;
    for (int i = threadIdx.x; i < 1024; i += 256) {
        int idx = base + i;
        if (idx < n) s += deg[idx];
    }
    sm[threadIdx.x] = s;
    __syncthreads();
    for (int off = 128; off > 0; off >>= 1) {
        if (threadIdx.x < off) sm[threadIdx.x] += sm[threadIdx.x + off];
        __syncthreads();
    }
    if (threadIdx.x == 0) blksum[blockIdx.x] = sm[0];
}

__global__ void scan_offsets_kernel(int* blksum, int nb, int* rowptr, int n) {
    if (threadIdx.x == 0 && blockIdx.x == 0) {
        int run = 0;
        for (int i = 0; i < nb; i++) { int v = blksum[i]; blksum[i] = run; run += v; }
        rowptr[n] = run;   // == E
    }
}

__global__ __launch_bounds__(256) void scan_write_kernel(const int* __restrict__ deg,
                                                         const int* __restrict__ blkoff,
                                                         int* __restrict__ rowptr, int n) {
    __shared__ int sm[256];
    int tid = threadIdx.x;
    int base = blockIdx.x * 1024 + tid * 4;
    int v0 = 0, v1 = 0, v2 = 0, v3 = 0;
    if (base + 0 < n) v0 = deg[base + 0];
    if (base + 1 < n) v1 = deg[base + 1];
    if (base + 2 < n) v2 = deg[base + 2];
    if (base + 3 < n) v3 = deg[base + 3];
    int tot = v0 + v1 + v2 + v3;
    sm[tid] = tot;
    __syncthreads();
    for (int off = 1; off < 256; off <<= 1) {
        int add = (tid >= off) ? sm[tid - off] : 0;
        __syncthreads();
        sm[tid] += add;
        __syncthreads();
    }
    int excl = blkoff[blockIdx.x] + sm[tid] - tot;
    if (base + 0 < n) rowptr[base + 0] = excl;
    if (base + 1 < n) rowptr[base + 1] = excl + v0;
    if (base + 2 < n) rowptr[base + 2] = excl + v0 + v1;
    if (base + 3 < n) rowptr[base + 3] = excl + v0 + v1 + v2;
}

__global__ void fill_csr_kernel(const int* __restrict__ src, const int* __restrict__ dst,
                                const int* __restrict__ rowptr, int* __restrict__ rowcur,
                                int* __restrict__ csr, int E) {
    int e = blockIdx.x * blockDim.x + threadIdx.x;
    if (e < E) {
        int d = dst[e];
        int pos = atomicAdd(&rowcur[d], 1);
        csr[rowptr[d] + pos] = src[e];
    }
}

// ----------------- GEMM: out[N,128] = A[N,128] @ W[128,128] -----------------
// block: 256 threads, 32 rows per block. W fully staged in LDS, A staged transposed.
__global__ __launch_bounds__(256) void gemm128_kernel(const float* __restrict__ A,
                                                      const float* __restrict__ W,
                                                      float* __restrict__ out) {
    __shared__ __align__(16) float Wl[128 * 128];  // 64 KB
    __shared__ __align__(16) float xT[128 * 32];   // 16 KB, xT[k][r]
    int tid = threadIdx.x;
    for (int i = tid; i < 128 * 128 / 4; i += 256)
        ((float4*)Wl)[i] = ((const float4*)W)[i];
    int row0 = blockIdx.x * 32;
    int r = tid >> 3, kq = tid & 7;
    const float4* xrow = (const float4*)(A + (size_t)(row0 + r) * 128 + kq * 16);
#pragma unroll
    for (int q = 0; q < 4; q++) {
        float4 v = xrow[q];
        int k = kq * 16 + q * 4;
        xT[(k + 0) * 32 + r] = v.x;
        xT[(k + 1) * 32 + r] = v.y;
        xT[(k + 2) * 32 + r] = v.z;
        xT[(k + 3) * 32 + r] = v.w;
    }
    __syncthreads();
    int cx = tid & 31, ry = tid >> 5;
    float4 acc0 = {0, 0, 0, 0}, acc1 = acc0, acc2 = acc0, acc3 = acc0;
#pragma unroll 4
    for (int k = 0; k < 128; k++) {
        float4 wv = *(const float4*)&Wl[k * 128 + cx * 4];
        float4 xv = *(const float4*)&xT[k * 32 + ry * 4];
        acc0.x += xv.x * wv.x; acc0.y += xv.x * wv.y; acc0.z += xv.x * wv.z; acc0.w += xv.x * wv.w;
        acc1.x += xv.y * wv.x; acc1.y += xv.y * wv.y; acc1.z += xv.y * wv.z; acc1.w += xv.y * wv.w;
        acc2.x += xv.z * wv.x; acc2.y += xv.z * wv.y; acc2.z += xv.z * wv.z; acc2.w += xv.z * wv.w;
        acc3.x += xv.w * wv.x; acc3.y += xv.w * wv.y; acc3.z += xv.w * wv.z; acc3.w += xv.w * wv.w;
    }
    float* o = out + (size_t)(row0 + ry * 4) * 128 + cx * 4;
    *(float4*)(o + 0)   = acc0;
    *(float4*)(o + 128) = acc1;
    *(float4*)(o + 256) = acc2;
    *(float4*)(o + 384) = acc3;
}

// ----------------- aggregation: one node per block (128 threads) -----------------
__global__ __launch_bounds__(128) void agg_kernel(const float* __restrict__ h,
                                                  const int* __restrict__ rowptr,
                                                  const int* __restrict__ csr,
                                                  const float* __restrict__ dinv,
                                                  const float* __restrict__ bias,
                                                  float* __restrict__ out, int relu) {
    int n = blockIdx.x;
    int d = threadIdx.x;
    float dn = dinv[n];
    float acc = h[(size_t)n * 128 + d] * dn * dn;   // self-loop term
    int beg = rowptr[n], end = rowptr[n + 1];
    for (int i = beg; i < end; i++) {
        int s = csr[i];
        float c = dinv[s] * dn;
        acc += h[(size_t)s * 128 + d] * c;
    }
    acc += bias[d];
    if (relu) acc = fmaxf(acc, 0.0f);
    out[(size_t)n * 128 + d] = acc;
}

// ----------------- link scoring -----------------
// 32 edges per block; emb [256] per edge staged transposed; Wp1 staged in 32KB chunks.
__global__ __launch_bounds__(256) void link_kernel(const float* __restrict__ h,
                                                   const int* __restrict__ eli,
                                                   const float* __restrict__ Wp1,
                                                   const float* __restrict__ bp1,
                                                   const float* __restrict__ Wp2,
                                                   const float* __restrict__ bp2,
                                                   float* __restrict__ out) {
    __shared__ __align__(16) float eT[256 * 32];  // 32 KB, eT[k][r]
    __shared__ __align__(16) float Wl[64 * 128];  // 32 KB
    int tid = threadIdx.x;
    int e0 = blockIdx.x * 32;
    int r = tid >> 3, kq = tid & 7;
    int es = eli[e0 + r];
    int et = eli[ELN + e0 + r];
    const float4* hs = (const float4*)(h + (size_t)es * 128 + kq * 16);
    const float4* ht = (const float4*)(h + (size_t)et * 128 + kq * 16);
#pragma unroll
    for (int q = 0; q < 4; q++) {
        float4 v = hs[q];
        int k = kq * 16 + q * 4;
        eT[(k + 0) * 32 + r] = v.x;
        eT[(k + 1) * 32 + r] = v.y;
        eT[(k + 2) * 32 + r] = v.z;
        eT[(k + 3) * 32 + r] = v.w;
    }
#pragma unroll
    for (int q = 0; q < 4; q++) {
        float4 v = ht[q];
        int k = 128 + kq * 16 + q * 4;
        eT[(k + 0) * 32 + r] = v.x;
        eT[(k + 1) * 32 + r] = v.y;
        eT[(k + 2) * 32 + r] = v.z;
        eT[(k + 3) * 32 + r] = v.w;
    }
    int cx = tid & 31, ry = tid >> 5;
    float4 acc0 = {0, 0, 0, 0}, acc1 = acc0, acc2 = acc0, acc3 = acc0;
    for (int kb = 0; kb < 4; kb++) {
        __syncthreads();  // protects eT (first iter) and Wl reuse (later iters)
        for (int i = tid; i < 64 * 128 / 4; i += 256)
            ((float4*)Wl)[i] = ((const float4*)(Wp1 + kb * 64 * 128))[i];
        __syncthreads();
#pragma unroll 4
        for (int kk = 0; kk < 64; kk++) {
            float4 wv = *(const float4*)&Wl[kk * 128 + cx * 4];
            float4 xv = *(const float4*)&eT[(kb * 64 + kk) * 32 + ry * 4];
            acc0.x += xv.x * wv.x; acc0.y += xv.x * wv.y; acc0.z += xv.x * wv.z; acc0.w += xv.x * wv.w;
            acc1.x += xv.y * wv.x; acc1.y += xv.y * wv.y; acc1.z += xv.y * wv.z; acc1.w += xv.y * wv.w;
            acc2.x += xv.z * wv.x; acc2.y += xv.z * wv.y; acc2.z += xv.z * wv.z; acc2.w += xv.z * wv.w;
            acc3.x += xv.w * wv.x; acc3.y += xv.w * wv.y; acc3.z += xv.w * wv.z; acc3.w += xv.w * wv.w;
        }
    }
    float4 bb = *(const float4*)(bp1 + cx * 4);
    float4 w2 = *(const float4*)(Wp2 + cx * 4);
    float p0 = fmaxf(acc0.x + bb.x, 0.f) * w2.x + fmaxf(acc0.y + bb.y, 0.f) * w2.y +
               fmaxf(acc0.z + bb.z, 0.f) * w2.z + fmaxf(acc0.w + bb.w, 0.f) * w2.w;
    float p1 = fmaxf(acc1.x + bb.x, 0.f) * w2.x + fmaxf(acc1.y + bb.y, 0.f) * w2.y +
               fmaxf(acc1.z + bb.z, 0.f) * w2.z + fmaxf(acc1.w + bb.w, 0.f) * w2.w;
    float p2 = fmaxf(acc2.x + bb.x, 0.f) * w2.x + fmaxf(acc2.y + bb.y, 0.f) * w2.y +
               fmaxf(acc2.z + bb.z, 0.f) * w2.z + fmaxf(acc2.w + bb.w, 0.f) * w2.w;
    float p3 = fmaxf(acc3.x + bb.x, 0.f) * w2.x + fmaxf(acc3.y + bb.y, 0.f) * w2.y +
               fmaxf(acc3.z + bb.z, 0.f) * w2.z + fmaxf(acc3.w + bb.w, 0.f) * w2.w;
#pragma unroll
    for (int off = 1; off < 32; off <<= 1) {
        p0 += __shfl_xor(p0, off);
        p1 += __shfl_xor(p1, off);
        p2 += __shfl_xor(p2, off);
        p3 += __shfl_xor(p3, off);
    }
    if (cx == 0) {
        float b2v = bp2[0];
        out[e0 + ry * 4 + 0] = p0 + b2v;
        out[e0 + ry * 4 + 1] = p1 + b2v;
        out[e0 + ry * 4 + 2] = p2 + b2v;
        out[e0 + ry * 4 + 3] = p3 + b2v;
    }
}

extern "C" void kernel_launch(void* const* d_in, const int* in_sizes, int n_in,
                              void* d_out, int out_size, void* d_ws, size_t ws_size,
                              hipStream_t stream) {
    const float* x   = (const float*)d_in[0];
    const int*   ei  = (const int*)d_in[1];
    const int*   eli = (const int*)d_in[2];
    const float* W1  = (const float*)d_in[3];
    const float* b1  = (const float*)d_in[4];
    const float* W2  = (const float*)d_in[5];
    const float* b2  = (const float*)d_in[6];
    const float* Wp1 = (const float*)d_in[7];
    const float* bp1 = (const float*)d_in[8];
    const float* Wp2 = (const float*)d_in[9];
    const float* bp2 = (const float*)d_in[10];
    float* out = (float*)d_out;

    char* w = (char*)d_ws;
    auto alloc = [&](size_t bytes) {
        char* p = w;
        w += (bytes + 255) & ~(size_t)255;
        return p;
    };
    int*   deg    = (int*)alloc((size_t)NN * 4);
    float* dinv   = (float*)alloc((size_t)NN * 4);
    int*   rowptr = (int*)alloc((size_t)(NN + 1) * 4);
    int*   rowcur = (int*)alloc((size_t)NN * 4);
    int*   blks   = (int*)alloc(1024);
    int*   csr    = (int*)alloc((size_t)EE * 4);
    float* hA     = (float*)alloc((size_t)NN * 128 * 4);
    float* hB     = (float*)alloc((size_t)NN * 128 * 4);

    const int* srcv = ei;       // row 0
    const int* dstv = ei + EE;  // row 1

    hipMemsetAsync(deg, 0, (size_t)NN * 4, stream);
    hipMemsetAsync(rowcur, 0, (size_t)NN * 4, stream);

    count_deg_kernel<<<(EE + 255) / 256, 256, 0, stream>>>(dstv, deg, EE);
    dinv_kernel<<<(NN + 255) / 256, 256, 0, stream>>>(deg, dinv, NN);
    int nb = (NN + 1023) / 1024;  // 98
    scan_partial_kernel<<<nb, 256, 0, stream>>>(deg, blks, NN);
    scan_offsets_kernel<<<1, 64, 0, stream>>>(blks, nb, rowptr, NN);
    scan_write_kernel<<<nb, 256, 0, stream>>>(deg, blks, rowptr, NN);
    fill_csr_kernel<<<(EE + 255) / 256, 256, 0, stream>>>(srcv, dstv, rowptr, rowcur, csr, EE);

    // layer 1: hA = x @ W1 ; hB = relu(agg(hA) + b1)
    gemm128_kernel<<<NN / 32, 256, 0, stream>>>(x, W1, hA);
    agg_kernel<<<NN, 128, 0, stream>>>(hA, rowptr, csr, dinv, b1, hB, 1);
    // layer 2: hA = hB @ W2 ; hB = agg(hA) + b2
    gemm128_kernel<<<NN / 32, 256, 0, stream>>>(hB, W2, hA);
    agg_kernel<<<NN, 128, 0, stream>>>(hA, rowptr, csr, dinv, b2, hB, 0);
    // link scoring
    link_kernel<<<ELN / 32, 256, 0, stream>>>(hB, eli, Wp1, bp1, Wp2, bp2, out);
}

// Round 2
// 470.338 us; speedup vs baseline: 1.8816x; 1.8816x over previous
//
#include <hip/hip_runtime.h>

#define NN 100000
#define EE 1600000
#define ELN 200000

typedef __attribute__((ext_vector_type(4))) float f32x4;
typedef __attribute__((ext_vector_type(8))) short short8;

__device__ __forceinline__ unsigned short f2bf(float f) {
    unsigned u = __builtin_bit_cast(unsigned, f);
    u += 0x7FFF + ((u >> 16) & 1);   // round-to-nearest-even
    return (unsigned short)(u >> 16);
}
__device__ __forceinline__ float bf2f(unsigned short h) {
    return __builtin_bit_cast(float, (unsigned)h << 16);
}

// ----------------- degree count -----------------
__global__ void count_deg_kernel(const int* __restrict__ dst, int* __restrict__ deg, int E) {
    int e = blockIdx.x * blockDim.x + threadIdx.x;
    if (e < E) atomicAdd(&deg[dst[e]], 1);
}

__global__ void dinv_kernel(const int* __restrict__ deg, float* __restrict__ dinv, int n) {
    int i = blockIdx.x * blockDim.x + threadIdx.x;
    if (i < n) dinv[i] = rsqrtf((float)deg[i] + 1.0f);
}

// ----------------- exclusive scan (3-phase) -----------------
__global__ __launch_bounds__(256) void scan_partial_kernel(const int* __restrict__ deg,
                                                           int* __restrict__ blksum, int n) {
    __shared__ int sm[256];
    int base = blockIdx.x * 1024;
    int s = 0;
    for (int i = threadIdx.x; i < 1024; i += 256) {
        int idx = base + i;
        if (idx < n) s += deg[idx];
    }
    sm[threadIdx.x] = s;
    __syncthreads();
    for (int off = 128; off > 0; off >>= 1) {
        if (threadIdx.x < off) sm[threadIdx.x] += sm[threadIdx.x + off];
        __syncthreads();
    }
    if (threadIdx.x == 0) blksum[blockIdx.x] = sm[0];
}

__global__ void scan_offsets_kernel(int* blksum, int nb, int* rowptr, int n) {
    if (threadIdx.x == 0 && blockIdx.x == 0) {
        int run = 0;
        for (int i = 0; i < nb; i++) { int v = blksum[i]; blksum[i] = run; run += v; }
        rowptr[n] = run;   // == E
    }
}

__global__ __launch_bounds__(256) void scan_write_kernel(const int* __restrict__ deg,
                                                         const int* __restrict__ blkoff,
                                                         int* __restrict__ rowptr, int n) {
    __shared__ int sm[256];
    int tid = threadIdx.x;
    int base = blockIdx.x * 1024 + tid * 4;
    int v0 = 0, v1 = 0, v2 = 0, v3 = 0;
    if (base + 0 < n) v0 = deg[base + 0];
    if (base + 1 < n) v1 = deg[base + 1];
    if (base + 2 < n) v2 = deg[base + 2];
    if (base + 3 < n) v3 = deg[base + 3];
    int tot = v0 + v1 + v2 + v3;
    sm[tid] = tot;
    __syncthreads();
    for (int off = 1; off < 256; off <<= 1) {
        int add = (tid >= off) ? sm[tid - off] : 0;
        __syncthreads();
        sm[tid] += add;
        __syncthreads();
    }
    int excl = blkoff[blockIdx.x] + sm[tid] - tot;
    if (base + 0 < n) rowptr[base + 0] = excl;
    if (base + 1 < n) rowptr[base + 1] = excl + v0;
    if (base + 2 < n) rowptr[base + 2] = excl + v0 + v1;
    if (base + 3 < n) rowptr[base + 3] = excl + v0 + v1 + v2;
}

__global__ void fill_csr_kernel(const int* __restrict__ src, const int* __restrict__ dst,
                                const int* __restrict__ rowptr, int* __restrict__ rowcur,
                                int* __restrict__ csr, int E) {
    int e = blockIdx.x * blockDim.x + threadIdx.x;
    if (e < E) {
        int d = dst[e];
        int pos = atomicAdd(&rowcur[d], 1);
        csr[rowptr[d] + pos] = src[e];
    }
}

// ----------------- GEMM via MFMA: out_bf16[N,128] = A[N,128] @ W[128,128] -----------------
// 256 threads = 4 waves; each wave does 16 rows x 128 cols per chunk; W^T staged bf16 in
// LDS with XOR swizzle (byte ^= (n&7)<<4) so stride-256B row reads are ~conflict-free.
template <bool A_IS_F32>
__global__ __launch_bounds__(256) void gemm_mfma_kernel(const void* __restrict__ Av,
                                                        const float* __restrict__ W,
                                                        unsigned short* __restrict__ out,
                                                        int nrows, int nchunks) {
    __shared__ __align__(16) char Wl[128 * 128 * 2];  // 32 KB: WT[n][k] bf16, swizzled
    int tid = threadIdx.x;
    const float4* W4 = (const float4*)W;
    for (int i4 = tid; i4 < 128 * 128 / 4; i4 += 256) {
        float4 v = W4[i4];
        int i = i4 * 4;
        int k = i >> 7, n0 = i & 127;
#pragma unroll
        for (int j = 0; j < 4; j++) {
            int n = n0 + j;
            int byte = (n * 256 + k * 2) ^ ((n & 7) << 4);
            *(unsigned short*)(Wl + byte) = f2bf(((const float*)&v)[j]);
        }
    }
    __syncthreads();
    int wid = tid >> 6, l = tid & 63;
    int lhi = l >> 4, llo = l & 15;
    for (int chunk = blockIdx.x; chunk < nchunks; chunk += gridDim.x) {
        int r0 = chunk * 64 + wid * 16;
        int arow = r0 + llo;
        f32x4 acc[8];
#pragma unroll
        for (int c = 0; c < 8; c++) acc[c] = (f32x4)0.0f;
#pragma unroll
        for (int ks = 0; ks < 4; ks++) {
            int koff = ks * 32 + lhi * 8;
            short8 a;
            if (arow < nrows) {
                if (A_IS_F32) {
                    const float* ap = (const float*)Av + (size_t)arow * 128 + koff;
                    float4 v0 = *(const float4*)ap;
                    float4 v1 = *(const float4*)(ap + 4);
                    a[0] = (short)f2bf(v0.x); a[1] = (short)f2bf(v0.y);
                    a[2] = (short)f2bf(v0.z); a[3] = (short)f2bf(v0.w);
                    a[4] = (short)f2bf(v1.x); a[5] = (short)f2bf(v1.y);
                    a[6] = (short)f2bf(v1.z); a[7] = (short)f2bf(v1.w);
                } else {
                    a = *(const short8*)((const unsigned short*)Av + (size_t)arow * 128 + koff);
                }
            } else {
                a = (short8)(short)0;
            }
#pragma unroll
            for (int c = 0; c < 8; c++) {
                int n = c * 16 + llo;
                int byte = (n * 256 + koff * 2) ^ ((n & 7) << 4);
                short8 b = *(const short8*)(Wl + byte);
                acc[c] = __builtin_amdgcn_mfma_f32_16x16x32_bf16(a, b, acc[c], 0, 0, 0);
            }
        }
#pragma unroll
        for (int c = 0; c < 8; c++) {
            int col = c * 16 + llo;
#pragma unroll
            for (int j = 0; j < 4; j++) {
                int row = r0 + lhi * 4 + j;
                if (row < nrows) out[(size_t)row * 128 + col] = f2bf(acc[c][j]);
            }
        }
    }
}

// ----------------- aggregation: one wave per node, bf16 gather, fp32 acc ---------------
__global__ __launch_bounds__(256) void agg_bf16_kernel(const unsigned short* __restrict__ h,
                                                       const int* __restrict__ rowptr,
                                                       const int* __restrict__ csr,
                                                       const float* __restrict__ dinv,
                                                       const float* __restrict__ bias,
                                                       unsigned short* __restrict__ out,
                                                       int relu) {
    int wid = threadIdx.x >> 6, l = threadIdx.x & 63;
    int node = blockIdx.x * 4 + wid;
    if (node >= NN) return;
    const unsigned* hp = (const unsigned*)h;  // one dword = 2 bf16 features
    float dn = dinv[node];
    unsigned sv = hp[(size_t)node * 64 + l];
    float a0 = bf2f((unsigned short)sv) * dn * dn;
    float a1 = bf2f((unsigned short)(sv >> 16)) * dn * dn;
    int beg = rowptr[node], end = rowptr[node + 1];
    int i = beg;
    for (; i + 4 <= end; i += 4) {
        int s0 = csr[i], s1 = csr[i + 1], s2 = csr[i + 2], s3 = csr[i + 3];
        unsigned v0 = hp[(size_t)s0 * 64 + l];
        unsigned v1 = hp[(size_t)s1 * 64 + l];
        unsigned v2 = hp[(size_t)s2 * 64 + l];
        unsigned v3 = hp[(size_t)s3 * 64 + l];
        float c0 = dinv[s0] * dn, c1 = dinv[s1] * dn;
        float c2 = dinv[s2] * dn, c3 = dinv[s3] * dn;
        a0 += c0 * bf2f((unsigned short)v0); a1 += c0 * bf2f((unsigned short)(v0 >> 16));
        a0 += c1 * bf2f((unsigned short)v1); a1 += c1 * bf2f((unsigned short)(v1 >> 16));
        a0 += c2 * bf2f((unsigned short)v2); a1 += c2 * bf2f((unsigned short)(v2 >> 16));
        a0 += c3 * bf2f((unsigned short)v3); a1 += c3 * bf2f((unsigned short)(v3 >> 16));
    }
    for (; i < end; i++) {
        int s = csr[i];
        unsigned v = hp[(size_t)s * 64 + l];
        float c = dinv[s] * dn;
        a0 += c * bf2f((unsigned short)v);
        a1 += c * bf2f((unsigned short)(v >> 16));
    }
    a0 += bias[l * 2];
    a1 += bias[l * 2 + 1];
    if (relu) { a0 = fmaxf(a0, 0.f); a1 = fmaxf(a1, 0.f); }
    ((unsigned*)out)[(size_t)node * 64 + l] = (unsigned)f2bf(a0) | ((unsigned)f2bf(a1) << 16);
}

// ----------------- link scoring via MFMA -----------------
// 4 waves x 16 edges; emb rows gathered straight from global as A-fragments;
// Wp1^T staged bf16+swizzled in LDS (64 KB); relu+Wp2 dot in fp32; shfl reduce.
__global__ __launch_bounds__(256) void link_mfma_kernel(const unsigned short* __restrict__ h,
                                                        const int* __restrict__ eli,
                                                        const float* __restrict__ Wp1,
                                                        const float* __restrict__ bp1,
                                                        const float* __restrict__ Wp2,
                                                        const float* __restrict__ bp2,
                                                        float* __restrict__ out) {
    __shared__ __align__(16) char Wl[128 * 256 * 2];  // 64 KB: WpT[n][k] bf16, swizzled
    int tid = threadIdx.x;
    const float4* W4 = (const float4*)Wp1;
    for (int i4 = tid; i4 < 256 * 128 / 4; i4 += 256) {
        float4 v = W4[i4];
        int i = i4 * 4;
        int k = i >> 7, n0 = i & 127;
#pragma unroll
        for (int j = 0; j < 4; j++) {
            int n = n0 + j;
            int byte = (n * 512 + k * 2) ^ ((n & 7) << 4);
            *(unsigned short*)(Wl + byte) = f2bf(((const float*)&v)[j]);
        }
    }
    __syncthreads();
    int wid = tid >> 6, l = tid & 63;
    int lhi = l >> 4, llo = l & 15;
    float bp1v[8], wp2v[8];
#pragma unroll
    for (int c = 0; c < 8; c++) {
        int col = c * 16 + llo;
        bp1v[c] = bp1[col];
        wp2v[c] = Wp2[col];
    }
    float b2 = bp2[0];
    for (int g = blockIdx.x; g < ELN / 64; g += gridDim.x) {
        int e_base = g * 64 + wid * 16;
        int ea = e_base + llo;
        int es = eli[ea], et = eli[ELN + ea];
        f32x4 acc[8];
#pragma unroll
        for (int c = 0; c < 8; c++) acc[c] = (f32x4)0.0f;
#pragma unroll
        for (int ks = 0; ks < 8; ks++) {
            int kg = ks * 32 + lhi * 8;          // emb k in [0,256)
            int row = (kg < 128) ? es : et;
            int koff = kg & 127;
            short8 a = *(const short8*)(h + (size_t)row * 128 + koff);
#pragma unroll
            for (int c = 0; c < 8; c++) {
                int n = c * 16 + llo;
                int byte = (n * 512 + kg * 2) ^ ((n & 7) << 4);
                short8 b = *(const short8*)(Wl + byte);
                acc[c] = __builtin_amdgcn_mfma_f32_16x16x32_bf16(a, b, acc[c], 0, 0, 0);
            }
        }
        float p0 = 0.f, p1 = 0.f, p2 = 0.f, p3 = 0.f;
#pragma unroll
        for (int c = 0; c < 8; c++) {
            p0 += fmaxf(acc[c][0] + bp1v[c], 0.f) * wp2v[c];
            p1 += fmaxf(acc[c][1] + bp1v[c], 0.f) * wp2v[c];
            p2 += fmaxf(acc[c][2] + bp1v[c], 0.f) * wp2v[c];
            p3 += fmaxf(acc[c][3] + bp1v[c], 0.f) * wp2v[c];
        }
#pragma unroll
        for (int off = 1; off < 16; off <<= 1) {
            p0 += __shfl_xor(p0, off);
            p1 += __shfl_xor(p1, off);
            p2 += __shfl_xor(p2, off);
            p3 += __shfl_xor(p3, off);
        }
        if (llo == 0) {
            int e = e_base + lhi * 4;
            out[e + 0] = p0 + b2;
            out[e + 1] = p1 + b2;
            out[e + 2] = p2 + b2;
            out[e + 3] = p3 + b2;
        }
    }
}

extern "C" void kernel_launch(void* const* d_in, const int* in_sizes, int n_in,
                              void* d_out, int out_size, void* d_ws, size_t ws_size,
                              hipStream_t stream) {
    const float* x   = (const float*)d_in[0];
    const int*   ei  = (const int*)d_in[1];
    const int*   eli = (const int*)d_in[2];
    const float* W1  = (const float*)d_in[3];
    const float* b1  = (const float*)d_in[4];
    const float* W2  = (const float*)d_in[5];
    const float* b2  = (const float*)d_in[6];
    const float* Wp1 = (const float*)d_in[7];
    const float* bp1 = (const float*)d_in[8];
    const float* Wp2 = (const float*)d_in[9];
    const float* bp2 = (const float*)d_in[10];
    float* out = (float*)d_out;

    char* w = (char*)d_ws;
    auto alloc = [&](size_t bytes) {
        char* p = w;
        w += (bytes + 255) & ~(size_t)255;
        return p;
    };
    int*            deg    = (int*)alloc((size_t)NN * 4);
    float*          dinv   = (float*)alloc((size_t)NN * 4);
    int*            rowptr = (int*)alloc((size_t)(NN + 1) * 4);
    int*            rowcur = (int*)alloc((size_t)NN * 4);
    int*            blks   = (int*)alloc(1024);
    int*            csr    = (int*)alloc((size_t)EE * 4);
    unsigned short* hA     = (unsigned short*)alloc((size_t)NN * 128 * 2);
    unsigned short* hB     = (unsigned short*)alloc((size_t)NN * 128 * 2);

    const int* srcv = ei;       // row 0
    const int* dstv = ei + EE;  // row 1

    hipMemsetAsync(deg, 0, (size_t)NN * 4, stream);
    hipMemsetAsync(rowcur, 0, (size_t)NN * 4, stream);

    count_deg_kernel<<<(EE + 255) / 256, 256, 0, stream>>>(dstv, deg, EE);
    dinv_kernel<<<(NN + 255) / 256, 256, 0, stream>>>(deg, dinv, NN);
    int nb = (NN + 1023) / 1024;  // 98
    scan_partial_kernel<<<nb, 256, 0, stream>>>(deg, blks, NN);
    scan_offsets_kernel<<<1, 64, 0, stream>>>(blks, nb, rowptr, NN);
    scan_write_kernel<<<nb, 256, 0, stream>>>(deg, blks, rowptr, NN);
    fill_csr_kernel<<<(EE + 255) / 256, 256, 0, stream>>>(srcv, dstv, rowptr, rowcur, csr, EE);

    int nchunks = (NN + 63) / 64;  // 1563
    // layer 1: hA = bf16(x @ W1); hB = bf16(relu(agg(hA) + b1))
    gemm_mfma_kernel<true><<<1024, 256, 0, stream>>>(x, W1, hA, NN, nchunks);
    agg_bf16_kernel<<<NN / 4, 256, 0, stream>>>(hA, rowptr, csr, dinv, b1, hB, 1);
    // layer 2: hA = bf16(hB @ W2); hB = bf16(agg(hA) + b2)
    gemm_mfma_kernel<false><<<1024, 256, 0, stream>>>(hB, W2, hA, NN, nchunks);
    agg_bf16_kernel<<<NN / 4, 256, 0, stream>>>(hA, rowptr, csr, dinv, b2, hB, 0);
    // link scoring
    link_mfma_kernel<<<1024, 256, 0, stream>>>(hB, eli, Wp1, bp1, Wp2, bp2, out);
}

// Round 3
// 445.298 us; speedup vs baseline: 1.9874x; 1.0562x over previous
//
#include <hip/hip_runtime.h>

#define NN 100000
#define EE 1600000
#define ELN 200000

#define NB 98           // dst buckets: dst >> 10, max 97
#define BKT_SHIFT 10
#define BKT_NODES 1024
#define MSB 256         // multisplit blocks
#define EPB (EE / MSB)  // 6250 edges per block

typedef __attribute__((ext_vector_type(4))) float f32x4;
typedef __attribute__((ext_vector_type(8))) short short8;

__device__ __forceinline__ unsigned short f2bf(float f) {
    unsigned u = __builtin_bit_cast(unsigned, f);
    u += 0x7FFF + ((u >> 16) & 1);   // round-to-nearest-even
    return (unsigned short)(u >> 16);
}
__device__ __forceinline__ float bf2f(unsigned short h) {
    return __builtin_bit_cast(float, (unsigned)h << 16);
}

// ----------------- multisplit CSR build -----------------
__global__ __launch_bounds__(256) void ms_hist_kernel(const int* __restrict__ dst,
                                                      int* __restrict__ histM) {
    __shared__ int cnt[NB];
    int tid = threadIdx.x;
    if (tid < NB) cnt[tid] = 0;
    __syncthreads();
    int base = blockIdx.x * EPB;
    for (int i = tid; i < EPB; i += 256)
        atomicAdd(&cnt[dst[base + i] >> BKT_SHIFT], 1);
    __syncthreads();
    if (tid < NB) histM[tid * MSB + blockIdx.x] = cnt[tid];
}

__global__ __launch_bounds__(256) void ms_scan_kernel(int* __restrict__ histM,
                                                      int* __restrict__ rowptr) {
    __shared__ int sm[256];
    __shared__ int carry;
    int tid = threadIdx.x;
    if (tid == 0) carry = 0;
    __syncthreads();
    const int TOT = NB * MSB;  // 25088, multiple of 256
    for (int base = 0; base < TOT; base += 256) {
        int v = histM[base + tid];
        sm[tid] = v;
        __syncthreads();
        for (int off = 1; off < 256; off <<= 1) {
            int add = (tid >= off) ? sm[tid - off] : 0;
            __syncthreads();
            sm[tid] += add;
            __syncthreads();
        }
        int incl = sm[tid];
        histM[base + tid] = carry + incl - v;  // exclusive
        __syncthreads();
        if (tid == 255) carry += incl;
        __syncthreads();
    }
    if (tid == 0) rowptr[NN] = EE;
}

__global__ __launch_bounds__(256) void ms_scatter_kernel(const int* __restrict__ src,
                                                         const int* __restrict__ dst,
                                                         const int* __restrict__ histO,
                                                         unsigned* __restrict__ tmp) {
    __shared__ int off[NB];
    int tid = threadIdx.x;
    if (tid < NB) off[tid] = histO[tid * MSB + blockIdx.x];
    __syncthreads();
    int base = blockIdx.x * EPB;
    for (int i = tid; i < EPB; i += 256) {
        int d = dst[base + i];
        int s = src[base + i];
        int b = d >> BKT_SHIFT;
        int pos = atomicAdd(&off[b], 1);
        tmp[pos] = ((unsigned)(d & (BKT_NODES - 1)) << 17) | (unsigned)s;
    }
}

// one block per bucket: build per-node counts, emit rowptr+dinv, scatter csr locally
__global__ __launch_bounds__(256) void bucket_csr_kernel(const unsigned* __restrict__ tmp,
                                                         const int* __restrict__ histO,
                                                         int* __restrict__ rowptr,
                                                         float* __restrict__ dinv,
                                                         int* __restrict__ csr) {
    __shared__ int cnt[BKT_NODES];
    __shared__ int lp[BKT_NODES];
    __shared__ int sm[256];
    int b = blockIdx.x;
    int tid = threadIdx.x;
    int gbase = histO[b * MSB];
    int gend = (b == NB - 1) ? EE : histO[(b + 1) * MSB];
    for (int i = tid; i < BKT_NODES; i += 256) cnt[i] = 0;
    __syncthreads();
    for (int i = gbase + tid; i < gend; i += 256)
        atomicAdd(&cnt[tmp[i] >> 17], 1);
    __syncthreads();
    // exclusive scan of cnt[1024] with 256 threads (4 elems each)
    int s0 = cnt[tid * 4], s1 = cnt[tid * 4 + 1], s2 = cnt[tid * 4 + 2], s3 = cnt[tid * 4 + 3];
    int tot = s0 + s1 + s2 + s3;
    sm[tid] = tot;
    __syncthreads();
    for (int off = 1; off < 256; off <<= 1) {
        int add = (tid >= off) ? sm[tid - off] : 0;
        __syncthreads();
        sm[tid] += add;
        __syncthreads();
    }
    int excl = sm[tid] - tot;
    lp[tid * 4] = excl;
    lp[tid * 4 + 1] = excl + s0;
    lp[tid * 4 + 2] = excl + s0 + s1;
    lp[tid * 4 + 3] = excl + s0 + s1 + s2;
    // emit rowptr + dinv, then reset cnt for position allocation
    int n0 = b << BKT_SHIFT;
#pragma unroll
    for (int q = 0; q < 4; q++) {
        int i = tid * 4 + q;
        int node = n0 + i;
        if (node < NN) {
            rowptr[node] = gbase + (q == 0 ? excl : lp[i]);
            int c = (q == 0) ? s0 : (q == 1 ? s1 : (q == 2 ? s2 : s3));
            dinv[node] = rsqrtf((float)c + 1.0f);
        }
    }
    cnt[tid * 4] = 0; cnt[tid * 4 + 1] = 0; cnt[tid * 4 + 2] = 0; cnt[tid * 4 + 3] = 0;
    __syncthreads();
    for (int i = gbase + tid; i < gend; i += 256) {
        unsigned p = tmp[i];
        int dl = p >> 17;
        int s = p & 0x1FFFF;
        int pos = atomicAdd(&cnt[dl], 1);
        csr[gbase + lp[dl] + pos] = s;
    }
}

// ----------------- GEMM via MFMA: out_bf16[N,128] = A[N,128] @ W[128,128] -----------------
template <bool A_IS_F32>
__global__ __launch_bounds__(256) void gemm_mfma_kernel(const void* __restrict__ Av,
                                                        const float* __restrict__ W,
                                                        unsigned short* __restrict__ out,
                                                        int nrows, int nchunks) {
    __shared__ __align__(16) char Wl[128 * 128 * 2];  // 32 KB: WT[n][k] bf16, swizzled
    int tid = threadIdx.x;
    const float4* W4 = (const float4*)W;
    for (int i4 = tid; i4 < 128 * 128 / 4; i4 += 256) {
        float4 v = W4[i4];
        int i = i4 * 4;
        int k = i >> 7, n0 = i & 127;
#pragma unroll
        for (int j = 0; j < 4; j++) {
            int n = n0 + j;
            int byte = (n * 256 + k * 2) ^ ((n & 7) << 4);
            *(unsigned short*)(Wl + byte) = f2bf(((const float*)&v)[j]);
        }
    }
    __syncthreads();
    int wid = tid >> 6, l = tid & 63;
    int lhi = l >> 4, llo = l & 15;
    for (int chunk = blockIdx.x; chunk < nchunks; chunk += gridDim.x) {
        int r0 = chunk * 64 + wid * 16;
        int arow = r0 + llo;
        f32x4 acc[8];
#pragma unroll
        for (int c = 0; c < 8; c++) acc[c] = (f32x4)0.0f;
#pragma unroll
        for (int ks = 0; ks < 4; ks++) {
            int koff = ks * 32 + lhi * 8;
            short8 a;
            if (arow < nrows) {
                if (A_IS_F32) {
                    const float* ap = (const float*)Av + (size_t)arow * 128 + koff;
                    float4 v0 = *(const float4*)ap;
                    float4 v1 = *(const float4*)(ap + 4);
                    a[0] = (short)f2bf(v0.x); a[1] = (short)f2bf(v0.y);
                    a[2] = (short)f2bf(v0.z); a[3] = (short)f2bf(v0.w);
                    a[4] = (short)f2bf(v1.x); a[5] = (short)f2bf(v1.y);
                    a[6] = (short)f2bf(v1.z); a[7] = (short)f2bf(v1.w);
                } else {
                    a = *(const short8*)((const unsigned short*)Av + (size_t)arow * 128 + koff);
                }
            } else {
                a = (short8)(short)0;
            }
#pragma unroll
            for (int c = 0; c < 8; c++) {
                int n = c * 16 + llo;
                int byte = (n * 256 + koff * 2) ^ ((n & 7) << 4);
                short8 bfr = *(const short8*)(Wl + byte);
                acc[c] = __builtin_amdgcn_mfma_f32_16x16x32_bf16(a, bfr, acc[c], 0, 0, 0);
            }
        }
#pragma unroll
        for (int c = 0; c < 8; c++) {
            int col = c * 16 + llo;
#pragma unroll
            for (int j = 0; j < 4; j++) {
                int row = r0 + lhi * 4 + j;
                if (row < nrows) out[(size_t)row * 128 + col] = f2bf(acc[c][j]);
            }
        }
    }
}

// ----------------- aggregation: one wave per node, bf16 gather, fp32 acc ---------------
__global__ __launch_bounds__(256) void agg_bf16_kernel(const unsigned short* __restrict__ h,
                                                       const int* __restrict__ rowptr,
                                                       const int* __restrict__ csr,
                                                       const float* __restrict__ dinv,
                                                       const float* __restrict__ bias,
                                                       unsigned short* __restrict__ out,
                                                       int relu) {
    int wid = threadIdx.x >> 6, l = threadIdx.x & 63;
    int node = blockIdx.x * 4 + wid;
    if (node >= NN) return;
    const unsigned* hp = (const unsigned*)h;  // one dword = 2 bf16 features
    float dn = dinv[node];
    unsigned sv = hp[(size_t)node * 64 + l];
    float a0 = bf2f((unsigned short)sv) * dn * dn;
    float a1 = bf2f((unsigned short)(sv >> 16)) * dn * dn;
    int beg = rowptr[node], end = rowptr[node + 1];
    int i = beg;
    for (; i + 4 <= end; i += 4) {
        int s0 = csr[i], s1 = csr[i + 1], s2 = csr[i + 2], s3 = csr[i + 3];
        unsigned v0 = hp[(size_t)s0 * 64 + l];
        unsigned v1 = hp[(size_t)s1 * 64 + l];
        unsigned v2 = hp[(size_t)s2 * 64 + l];
        unsigned v3 = hp[(size_t)s3 * 64 + l];
        float c0 = dinv[s0] * dn, c1 = dinv[s1] * dn;
        float c2 = dinv[s2] * dn, c3 = dinv[s3] * dn;
        a0 += c0 * bf2f((unsigned short)v0); a1 += c0 * bf2f((unsigned short)(v0 >> 16));
        a0 += c1 * bf2f((unsigned short)v1); a1 += c1 * bf2f((unsigned short)(v1 >> 16));
        a0 += c2 * bf2f((unsigned short)v2); a1 += c2 * bf2f((unsigned short)(v2 >> 16));
        a0 += c3 * bf2f((unsigned short)v3); a1 += c3 * bf2f((unsigned short)(v3 >> 16));
    }
    for (; i < end; i++) {
        int s = csr[i];
        unsigned v = hp[(size_t)s * 64 + l];
        float c = dinv[s] * dn;
        a0 += c * bf2f((unsigned short)v);
        a1 += c * bf2f((unsigned short)(v >> 16));
    }
    a0 += bias[l * 2];
    a1 += bias[l * 2 + 1];
    if (relu) { a0 = fmaxf(a0, 0.f); a1 = fmaxf(a1, 0.f); }
    ((unsigned*)out)[(size_t)node * 64 + l] = (unsigned)f2bf(a0) | ((unsigned)f2bf(a1) << 16);
}

// ----------------- link scoring via MFMA -----------------
__global__ __launch_bounds__(256) void link_mfma_kernel(const unsigned short* __restrict__ h,
                                                        const int* __restrict__ eli,
                                                        const float* __restrict__ Wp1,
                                                        const float* __restrict__ bp1,
                                                        const float* __restrict__ Wp2,
                                                        const float* __restrict__ bp2,
                                                        float* __restrict__ out) {
    __shared__ __align__(16) char Wl[128 * 256 * 2];  // 64 KB: WpT[n][k] bf16, swizzled
    int tid = threadIdx.x;
    const float4* W4 = (const float4*)Wp1;
    for (int i4 = tid; i4 < 256 * 128 / 4; i4 += 256) {
        float4 v = W4[i4];
        int i = i4 * 4;
        int k = i >> 7, n0 = i & 127;
#pragma unroll
        for (int j = 0; j < 4; j++) {
            int n = n0 + j;
            int byte = (n * 512 + k * 2) ^ ((n & 7) << 4);
            *(unsigned short*)(Wl + byte) = f2bf(((const float*)&v)[j]);
        }
    }
    __syncthreads();
    int wid = tid >> 6, l = tid & 63;
    int lhi = l >> 4, llo = l & 15;
    float bp1v[8], wp2v[8];
#pragma unroll
    for (int c = 0; c < 8; c++) {
        int col = c * 16 + llo;
        bp1v[c] = bp1[col];
        wp2v[c] = Wp2[col];
    }
    float b2 = bp2[0];
    for (int g = blockIdx.x; g < ELN / 64; g += gridDim.x) {
        int e_base = g * 64 + wid * 16;
        int ea = e_base + llo;
        int es = eli[ea], et = eli[ELN + ea];
        f32x4 acc[8];
#pragma unroll
        for (int c = 0; c < 8; c++) acc[c] = (f32x4)0.0f;
#pragma unroll
        for (int ks = 0; ks < 8; ks++) {
            int kg = ks * 32 + lhi * 8;          // emb k in [0,256)
            int row = (kg < 128) ? es : et;
            int koff = kg & 127;
            short8 a = *(const short8*)(h + (size_t)row * 128 + koff);
#pragma unroll
            for (int c = 0; c < 8; c++) {
                int n = c * 16 + llo;
                int byte = (n * 512 + kg * 2) ^ ((n & 7) << 4);
                short8 bfr = *(const short8*)(Wl + byte);
                acc[c] = __builtin_amdgcn_mfma_f32_16x16x32_bf16(a, bfr, acc[c], 0, 0, 0);
            }
        }
        float p0 = 0.f, p1 = 0.f, p2 = 0.f, p3 = 0.f;
#pragma unroll
        for (int c = 0; c < 8; c++) {
            p0 += fmaxf(acc[c][0] + bp1v[c], 0.f) * wp2v[c];
            p1 += fmaxf(acc[c][1] + bp1v[c], 0.f) * wp2v[c];
            p2 += fmaxf(acc[c][2] + bp1v[c], 0.f) * wp2v[c];
            p3 += fmaxf(acc[c][3] + bp1v[c], 0.f) * wp2v[c];
        }
#pragma unroll
        for (int off = 1; off < 16; off <<= 1) {
            p0 += __shfl_xor(p0, off);
            p1 += __shfl_xor(p1, off);
            p2 += __shfl_xor(p2, off);
            p3 += __shfl_xor(p3, off);
        }
        if (llo == 0) {
            int e = e_base + lhi * 4;
            out[e + 0] = p0 + b2;
            out[e + 1] = p1 + b2;
            out[e + 2] = p2 + b2;
            out[e + 3] = p3 + b2;
        }
    }
}

extern "C" void kernel_launch(void* const* d_in, const int* in_sizes, int n_in,
                              void* d_out, int out_size, void* d_ws, size_t ws_size,
                              hipStream_t stream) {
    const float* x   = (const float*)d_in[0];
    const int*   ei  = (const int*)d_in[1];
    const int*   eli = (const int*)d_in[2];
    const float* W1  = (const float*)d_in[3];
    const float* b1  = (const float*)d_in[4];
    const float* W2  = (const float*)d_in[5];
    const float* b2  = (const float*)d_in[6];
    const float* Wp1 = (const float*)d_in[7];
    const float* bp1 = (const float*)d_in[8];
    const float* Wp2 = (const float*)d_in[9];
    const float* bp2 = (const float*)d_in[10];
    float* out = (float*)d_out;

    char* w = (char*)d_ws;
    auto alloc = [&](size_t bytes) {
        char* p = w;
        w += (bytes + 255) & ~(size_t)255;
        return p;
    };
    float*          dinv   = (float*)alloc((size_t)NN * 4);
    int*            rowptr = (int*)alloc((size_t)(NN + 1) * 4);
    int*            histM  = (int*)alloc((size_t)NB * MSB * 4);
    unsigned*       tmp    = (unsigned*)alloc((size_t)EE * 4);
    int*            csr    = (int*)alloc((size_t)EE * 4);
    unsigned short* hA     = (unsigned short*)alloc((size_t)NN * 128 * 2);
    unsigned short* hB     = (unsigned short*)alloc((size_t)NN * 128 * 2);

    const int* srcv = ei;       // row 0
    const int* dstv = ei + EE;  // row 1

    // CSR build: multisplit by dst bucket, then per-bucket local CSR (+rowptr,+dinv)
    ms_hist_kernel<<<MSB, 256, 0, stream>>>(dstv, histM);
    ms_scan_kernel<<<1, 256, 0, stream>>>(histM, rowptr);
    ms_scatter_kernel<<<MSB, 256, 0, stream>>>(srcv, dstv, histM, tmp);
    bucket_csr_kernel<<<NB, 256, 0, stream>>>(tmp, histM, rowptr, dinv, csr);

    int nchunks = (NN + 63) / 64;  // 1563
    // layer 1: hA = bf16(x @ W1); hB = bf16(relu(agg(hA) + b1))
    gemm_mfma_kernel<true><<<1024, 256, 0, stream>>>(x, W1, hA, NN, nchunks);
    agg_bf16_kernel<<<NN / 4, 256, 0, stream>>>(hA, rowptr, csr, dinv, b1, hB, 1);
    // layer 2: hA = bf16(hB @ W2); hB = bf16(agg(hA) + b2)
    gemm_mfma_kernel<false><<<1024, 256, 0, stream>>>(hB, W2, hA, NN, nchunks);
    agg_bf16_kernel<<<NN / 4, 256, 0, stream>>>(hA, rowptr, csr, dinv, b2, hB, 0);
    // link scoring
    link_mfma_kernel<<<1024, 256, 0, stream>>>(hB, eli, Wp1, bp1, Wp2, bp2, out);
}

// Round 4
// 353.261 us; speedup vs baseline: 2.5052x; 1.2605x over previous
//
#include <hip/hip_runtime.h>

#define NN 100000
#define EE 1600000
#define ELN 200000

#define NB 98           // dst buckets: dst >> 10, max 97
#define BKT_SHIFT 10
#define BKT_NODES 1024
#define MSB 256         // multisplit blocks
#define EPB (EE / MSB)  // 6250 edges per block

typedef __attribute__((ext_vector_type(4))) float f32x4;
typedef __attribute__((ext_vector_type(8))) short short8;

__device__ __forceinline__ unsigned short f2bf(float f) {
    unsigned u = __builtin_bit_cast(unsigned, f);
    u += 0x7FFF + ((u >> 16) & 1);   // round-to-nearest-even
    return (unsigned short)(u >> 16);
}
__device__ __forceinline__ float bf2f(unsigned short h) {
    return __builtin_bit_cast(float, (unsigned)h << 16);
}

// ----------------- multisplit CSR build -----------------
__global__ __launch_bounds__(256) void ms_hist_kernel(const int* __restrict__ dst,
                                                      int* __restrict__ histM) {
    __shared__ int cnt[NB];
    int tid = threadIdx.x;
    if (tid < NB) cnt[tid] = 0;
    __syncthreads();
    int base = blockIdx.x * EPB;
    for (int i = tid; i < EPB; i += 256)
        atomicAdd(&cnt[dst[base + i] >> BKT_SHIFT], 1);
    __syncthreads();
    if (tid < NB) histM[tid * MSB + blockIdx.x] = cnt[tid];
}

// one-pass scan: 256 threads x 98 contiguous elements each (25088 total)
__global__ __launch_bounds__(256) void ms_scan_kernel(int* __restrict__ histM,
                                                      int* __restrict__ rowptr) {
    __shared__ int sm[256];
    int tid = threadIdx.x;
    const int CPT = NB * MSB / 256;  // 98
    int base = tid * CPT;
    int s = 0;
    for (int i = 0; i < CPT; i++) s += histM[base + i];
    sm[tid] = s;
    __syncthreads();
    for (int off = 1; off < 256; off <<= 1) {
        int add = (tid >= off) ? sm[tid - off] : 0;
        __syncthreads();
        sm[tid] += add;
        __syncthreads();
    }
    int run = sm[tid] - s;  // exclusive prefix of this thread's run
    for (int i = 0; i < CPT; i++) {
        int v = histM[base + i];
        histM[base + i] = run;
        run += v;
    }
    if (tid == 0) rowptr[NN] = EE;
}

__global__ __launch_bounds__(256) void ms_scatter_kernel(const int* __restrict__ src,
                                                         const int* __restrict__ dst,
                                                         const int* __restrict__ histO,
                                                         unsigned* __restrict__ tmp) {
    __shared__ int off[NB];
    int tid = threadIdx.x;
    if (tid < NB) off[tid] = histO[tid * MSB + blockIdx.x];
    __syncthreads();
    int base = blockIdx.x * EPB;
    for (int i = tid; i < EPB; i += 256) {
        int d = dst[base + i];
        int s = src[base + i];
        int b = d >> BKT_SHIFT;
        int pos = atomicAdd(&off[b], 1);
        tmp[pos] = ((unsigned)(d & (BKT_NODES - 1)) << 17) | (unsigned)s;
    }
}

// one block per bucket: build per-node counts, emit rowptr+dinv, scatter csr locally
__global__ __launch_bounds__(256) void bucket_csr_kernel(const unsigned* __restrict__ tmp,
                                                         const int* __restrict__ histO,
                                                         int* __restrict__ rowptr,
                                                         float* __restrict__ dinv,
                                                         int* __restrict__ csr) {
    __shared__ int cnt[BKT_NODES];
    __shared__ int lp[BKT_NODES];
    __shared__ int sm[256];
    int b = blockIdx.x;
    int tid = threadIdx.x;
    int gbase = histO[b * MSB];
    int gend = (b == NB - 1) ? EE : histO[(b + 1) * MSB];
    for (int i = tid; i < BKT_NODES; i += 256) cnt[i] = 0;
    __syncthreads();
    for (int i = gbase + tid; i < gend; i += 256)
        atomicAdd(&cnt[tmp[i] >> 17], 1);
    __syncthreads();
    // exclusive scan of cnt[1024] with 256 threads (4 elems each)
    int s0 = cnt[tid * 4], s1 = cnt[tid * 4 + 1], s2 = cnt[tid * 4 + 2], s3 = cnt[tid * 4 + 3];
    int tot = s0 + s1 + s2 + s3;
    sm[tid] = tot;
    __syncthreads();
    for (int off = 1; off < 256; off <<= 1) {
        int add = (tid >= off) ? sm[tid - off] : 0;
        __syncthreads();
        sm[tid] += add;
        __syncthreads();
    }
    int excl = sm[tid] - tot;
    lp[tid * 4] = excl;
    lp[tid * 4 + 1] = excl + s0;
    lp[tid * 4 + 2] = excl + s0 + s1;
    lp[tid * 4 + 3] = excl + s0 + s1 + s2;
    // emit rowptr + dinv, then reset cnt for position allocation
    int n0 = b << BKT_SHIFT;
#pragma unroll
    for (int q = 0; q < 4; q++) {
        int i = tid * 4 + q;
        int node = n0 + i;
        if (node < NN) {
            rowptr[node] = gbase + (q == 0 ? excl : lp[i]);
            int c = (q == 0) ? s0 : (q == 1 ? s1 : (q == 2 ? s2 : s3));
            dinv[node] = rsqrtf((float)c + 1.0f);
        }
    }
    cnt[tid * 4] = 0; cnt[tid * 4 + 1] = 0; cnt[tid * 4 + 2] = 0; cnt[tid * 4 + 3] = 0;
    __syncthreads();
    for (int i = gbase + tid; i < gend; i += 256) {
        unsigned p = tmp[i];
        int dl = p >> 17;
        int s = p & 0x1FFFF;
        int pos = atomicAdd(&cnt[dl], 1);
        csr[gbase + lp[dl] + pos] = s;
    }
}

// ----------------- GEMM via MFMA: out_bf16[N,128] = A[N,128] @ W[128,128] -----------------
template <bool A_IS_F32>
__global__ __launch_bounds__(256) void gemm_mfma_kernel(const void* __restrict__ Av,
                                                        const float* __restrict__ W,
                                                        unsigned short* __restrict__ out,
                                                        int nrows, int nchunks) {
    __shared__ __align__(16) char Wl[128 * 128 * 2];  // 32 KB: WT[n][k] bf16, swizzled
    int tid = threadIdx.x;
    const float4* W4 = (const float4*)W;
    for (int i4 = tid; i4 < 128 * 128 / 4; i4 += 256) {
        float4 v = W4[i4];
        int i = i4 * 4;
        int k = i >> 7, n0 = i & 127;
#pragma unroll
        for (int j = 0; j < 4; j++) {
            int n = n0 + j;
            int byte = (n * 256 + k * 2) ^ ((n & 7) << 4);
            *(unsigned short*)(Wl + byte) = f2bf(((const float*)&v)[j]);
        }
    }
    __syncthreads();
    int wid = tid >> 6, l = tid & 63;
    int lhi = l >> 4, llo = l & 15;
    for (int chunk = blockIdx.x; chunk < nchunks; chunk += gridDim.x) {
        int r0 = chunk * 64 + wid * 16;
        int arow = r0 + llo;
        f32x4 acc[8];
#pragma unroll
        for (int c = 0; c < 8; c++) acc[c] = (f32x4)0.0f;
#pragma unroll
        for (int ks = 0; ks < 4; ks++) {
            int koff = ks * 32 + lhi * 8;
            short8 a;
            if (arow < nrows) {
                if (A_IS_F32) {
                    const float* ap = (const float*)Av + (size_t)arow * 128 + koff;
                    float4 v0 = *(const float4*)ap;
                    float4 v1 = *(const float4*)(ap + 4);
                    a[0] = (short)f2bf(v0.x); a[1] = (short)f2bf(v0.y);
                    a[2] = (short)f2bf(v0.z); a[3] = (short)f2bf(v0.w);
                    a[4] = (short)f2bf(v1.x); a[5] = (short)f2bf(v1.y);
                    a[6] = (short)f2bf(v1.z); a[7] = (short)f2bf(v1.w);
                } else {
                    a = *(const short8*)((const unsigned short*)Av + (size_t)arow * 128 + koff);
                }
            } else {
                a = (short8)(short)0;
            }
#pragma unroll
            for (int c = 0; c < 8; c++) {
                int n = c * 16 + llo;
                int byte = (n * 256 + koff * 2) ^ ((n & 7) << 4);
                short8 bfr = *(const short8*)(Wl + byte);
                acc[c] = __builtin_amdgcn_mfma_f32_16x16x32_bf16(a, bfr, acc[c], 0, 0, 0);
            }
        }
#pragma unroll
        for (int c = 0; c < 8; c++) {
            int col = c * 16 + llo;
#pragma unroll
            for (int j = 0; j < 4; j++) {
                int row = r0 + lhi * 4 + j;
                if (row < nrows) out[(size_t)row * 128 + col] = f2bf(acc[c][j]);
            }
        }
    }
}

// ----------------- aggregation: one wave per node, bf16 gather, fp32 acc ---------------
__global__ __launch_bounds__(256) void agg_bf16_kernel(const unsigned short* __restrict__ h,
                                                       const int* __restrict__ rowptr,
                                                       const int* __restrict__ csr,
                                                       const float* __restrict__ dinv,
                                                       const float* __restrict__ bias,
                                                       unsigned short* __restrict__ out,
                                                       int relu) {
    int wid = threadIdx.x >> 6, l = threadIdx.x & 63;
    int node = blockIdx.x * 4 + wid;
    if (node >= NN) return;
    const unsigned* hp = (const unsigned*)h;  // one dword = 2 bf16 features
    float dn = dinv[node];
    unsigned sv = hp[(size_t)node * 64 + l];
    float a0 = bf2f((unsigned short)sv) * dn * dn;
    float a1 = bf2f((unsigned short)(sv >> 16)) * dn * dn;
    int beg = rowptr[node], end = rowptr[node + 1];
    int i = beg;
    for (; i + 4 <= end; i += 4) {
        int s0 = csr[i], s1 = csr[i + 1], s2 = csr[i + 2], s3 = csr[i + 3];
        unsigned v0 = hp[(size_t)s0 * 64 + l];
        unsigned v1 = hp[(size_t)s1 * 64 + l];
        unsigned v2 = hp[(size_t)s2 * 64 + l];
        unsigned v3 = hp[(size_t)s3 * 64 + l];
        float c0 = dinv[s0] * dn, c1 = dinv[s1] * dn;
        float c2 = dinv[s2] * dn, c3 = dinv[s3] * dn;
        a0 += c0 * bf2f((unsigned short)v0); a1 += c0 * bf2f((unsigned short)(v0 >> 16));
        a0 += c1 * bf2f((unsigned short)v1); a1 += c1 * bf2f((unsigned short)(v1 >> 16));
        a0 += c2 * bf2f((unsigned short)v2); a1 += c2 * bf2f((unsigned short)(v2 >> 16));
        a0 += c3 * bf2f((unsigned short)v3); a1 += c3 * bf2f((unsigned short)(v3 >> 16));
    }
    for (; i < end; i++) {
        int s = csr[i];
        unsigned v = hp[(size_t)s * 64 + l];
        float c = dinv[s] * dn;
        a0 += c * bf2f((unsigned short)v);
        a1 += c * bf2f((unsigned short)(v >> 16));
    }
    a0 += bias[l * 2];
    a1 += bias[l * 2 + 1];
    if (relu) { a0 = fmaxf(a0, 0.f); a1 = fmaxf(a1, 0.f); }
    ((unsigned*)out)[(size_t)node * 64 + l] = (unsigned)f2bf(a0) | ((unsigned)f2bf(a1) << 16);
}

// ----------------- link scoring via MFMA -----------------
__global__ __launch_bounds__(256) void link_mfma_kernel(const unsigned short* __restrict__ h,
                                                        const int* __restrict__ eli,
                                                        const float* __restrict__ Wp1,
                                                        const float* __restrict__ bp1,
                                                        const float* __restrict__ Wp2,
                                                        const float* __restrict__ bp2,
                                                        float* __restrict__ out) {
    __shared__ __align__(16) char Wl[128 * 256 * 2];  // 64 KB: WpT[n][k] bf16, swizzled
    int tid = threadIdx.x;
    const float4* W4 = (const float4*)Wp1;
    for (int i4 = tid; i4 < 256 * 128 / 4; i4 += 256) {
        float4 v = W4[i4];
        int i = i4 * 4;
        int k = i >> 7, n0 = i & 127;
#pragma unroll
        for (int j = 0; j < 4; j++) {
            int n = n0 + j;
            int byte = (n * 512 + k * 2) ^ ((n & 7) << 4);
            *(unsigned short*)(Wl + byte) = f2bf(((const float*)&v)[j]);
        }
    }
    __syncthreads();
    int wid = tid >> 6, l = tid & 63;
    int lhi = l >> 4, llo = l & 15;
    float bp1v[8], wp2v[8];
#pragma unroll
    for (int c = 0; c < 8; c++) {
        int col = c * 16 + llo;
        bp1v[c] = bp1[col];
        wp2v[c] = Wp2[col];
    }
    float b2 = bp2[0];
    for (int g = blockIdx.x; g < ELN / 64; g += gridDim.x) {
        int e_base = g * 64 + wid * 16;
        int ea = e_base + llo;
        int es = eli[ea], et = eli[ELN + ea];
        f32x4 acc[8];
#pragma unroll
        for (int c = 0; c < 8; c++) acc[c] = (f32x4)0.0f;
#pragma unroll
        for (int ks = 0; ks < 8; ks++) {
            int kg = ks * 32 + lhi * 8;          // emb k in [0,256)
            int row = (kg < 128) ? es : et;
            int koff = kg & 127;
            short8 a = *(const short8*)(h + (size_t)row * 128 + koff);
#pragma unroll
            for (int c = 0; c < 8; c++) {
                int n = c * 16 + llo;
                int byte = (n * 512 + kg * 2) ^ ((n & 7) << 4);
                short8 bfr = *(const short8*)(Wl + byte);
                acc[c] = __builtin_amdgcn_mfma_f32_16x16x32_bf16(a, bfr, acc[c], 0, 0, 0);
            }
        }
        float p0 = 0.f, p1 = 0.f, p2 = 0.f, p3 = 0.f;
#pragma unroll
        for (int c = 0; c < 8; c++) {
            p0 += fmaxf(acc[c][0] + bp1v[c], 0.f) * wp2v[c];
            p1 += fmaxf(acc[c][1] + bp1v[c], 0.f) * wp2v[c];
            p2 += fmaxf(acc[c][2] + bp1v[c], 0.f) * wp2v[c];
            p3 += fmaxf(acc[c][3] + bp1v[c], 0.f) * wp2v[c];
        }
#pragma unroll
        for (int off = 1; off < 16; off <<= 1) {
            p0 += __shfl_xor(p0, off);
            p1 += __shfl_xor(p1, off);
            p2 += __shfl_xor(p2, off);
            p3 += __shfl_xor(p3, off);
        }
        if (llo == 0) {
            int e = e_base + lhi * 4;
            out[e + 0] = p0 + b2;
            out[e + 1] = p1 + b2;
            out[e + 2] = p2 + b2;
            out[e + 3] = p3 + b2;
        }
    }
}

extern "C" void kernel_launch(void* const* d_in, const int* in_sizes, int n_in,
                              void* d_out, int out_size, void* d_ws, size_t ws_size,
                              hipStream_t stream) {
    const float* x   = (const float*)d_in[0];
    const int*   ei  = (const int*)d_in[1];
    const int*   eli = (const int*)d_in[2];
    const float* W1  = (const float*)d_in[3];
    const float* b1  = (const float*)d_in[4];
    const float* W2  = (const float*)d_in[5];
    const float* b2  = (const float*)d_in[6];
    const float* Wp1 = (const float*)d_in[7];
    const float* bp1 = (const float*)d_in[8];
    const float* Wp2 = (const float*)d_in[9];
    const float* bp2 = (const float*)d_in[10];
    float* out = (float*)d_out;

    char* w = (char*)d_ws;
    auto alloc = [&](size_t bytes) {
        char* p = w;
        w += (bytes + 255) & ~(size_t)255;
        return p;
    };
    float*          dinv   = (float*)alloc((size_t)NN * 4);
    int*            rowptr = (int*)alloc((size_t)(NN + 1) * 4);
    int*            histM  = (int*)alloc((size_t)NB * MSB * 4);
    unsigned*       tmp    = (unsigned*)alloc((size_t)EE * 4);
    int*            csr    = (int*)alloc((size_t)EE * 4);
    unsigned short* hA     = (unsigned short*)alloc((size_t)NN * 128 * 2);
    unsigned short* hB     = (unsigned short*)alloc((size_t)NN * 128 * 2);

    const int* srcv = ei;       // row 0
    const int* dstv = ei + EE;  // row 1

    // CSR build: multisplit by dst bucket, then per-bucket local CSR (+rowptr,+dinv)
    ms_hist_kernel<<<MSB, 256, 0, stream>>>(dstv, histM);
    ms_scan_kernel<<<1, 256, 0, stream>>>(histM, rowptr);
    ms_scatter_kernel<<<MSB, 256, 0, stream>>>(srcv, dstv, histM, tmp);
    bucket_csr_kernel<<<NB, 256, 0, stream>>>(tmp, histM, rowptr, dinv, csr);

    int nchunks = (NN + 63) / 64;  // 1563
    // layer 1: hA = bf16(x @ W1); hB = bf16(relu(agg(hA) + b1))
    gemm_mfma_kernel<true><<<1024, 256, 0, stream>>>(x, W1, hA, NN, nchunks);
    agg_bf16_kernel<<<NN / 4, 256, 0, stream>>>(hA, rowptr, csr, dinv, b1, hB, 1);
    // layer 2: hA = bf16(hB @ W2); hB = bf16(agg(hA) + b2)
    gemm_mfma_kernel<false><<<1024, 256, 0, stream>>>(hB, W2, hA, NN, nchunks);
    agg_bf16_kernel<<<NN / 4, 256, 0, stream>>>(hA, rowptr, csr, dinv, b2, hB, 0);
    // link scoring
    link_mfma_kernel<<<1024, 256, 0, stream>>>(hB, eli, Wp1, bp1, Wp2, bp2, out);
}